// Round 4
// baseline (224.336 us; speedup 1.0000x reference)
//
#include <hip/hip_runtime.h>

// Virial: v_graph[g] = sum_e [-2*w_e * disp_e disp_e^T] * (#endpoints of e in g)
// Symmetric 3x3 per edge -> 6 components. Edge -> graph directly via
// batch[edge_index[0/1]]; the N x 3 x 3 atom intermediate is never formed.
//
// Structure: main kernel accumulates per-block 64x6 partials in LDS (native
// ds_add_f32 atomics), writes them to d_ws (NO global atomics - fp32 global
// atomicAdd lowers to a CAS loop and cost ~200us in round 3). Two small
// atomic-free reduction kernels collapse the partials into d_out.

#define NG 64
#define NCOMP 6
#define NPART (NG * NCOMP)      // 384 floats per block partial
#define ACC_STRIDE 7            // 6 used, stride 7 (spread across 32 banks)
#define RED1_BLOCKS 64

__device__ __forceinline__ void lds_add(float* p, float v) {
    // WORKGROUP scope, relaxed -> native ds_add_f32 (no CAS loop).
    __hip_atomic_fetch_add(p, v, __ATOMIC_RELAXED, __HIP_MEMORY_SCOPE_WORKGROUP);
}

__global__ void zero_out_kernel(float* __restrict__ out, int n) {
    int i = blockIdx.x * blockDim.x + threadIdx.x;
    if (i < n) out[i] = 0.0f;
}

__global__ __launch_bounds__(256) void virial_partials(
    const float* __restrict__ disp,       // E*3
    const float* __restrict__ edge_w,     // E
    const int*   __restrict__ edge_index, // 2*E
    const int*   __restrict__ batch,      // N, sorted
    float* __restrict__ partials,         // [nblk][NPART] in d_ws, or null
    float* __restrict__ out,              // fallback target (pre-zeroed) if partials==null
    int E)
{
    __shared__ float acc[NG * ACC_STRIDE];
    for (int i = threadIdx.x; i < NG * ACC_STRIDE; i += blockDim.x) acc[i] = 0.0f;
    __syncthreads();

    const int nquads = E >> 2;
    const int tid    = blockIdx.x * blockDim.x + threadIdx.x;
    const int stride = gridDim.x * blockDim.x;

    const float4* __restrict__ disp4 = (const float4*)disp;
    const float4* __restrict__ w4    = (const float4*)edge_w;
    const int4*   __restrict__ src4  = (const int4*)edge_index;
    const int4*   __restrict__ dst4  = (const int4*)(edge_index + E);

    for (int q = tid; q < nquads; q += stride) {
        float4 d0 = disp4[q * 3 + 0];
        float4 d1 = disp4[q * 3 + 1];
        float4 d2 = disp4[q * 3 + 2];
        float4 w  = w4[q];
        int4   s  = src4[q];
        int4   t  = dst4[q];

        float dx[4] = {d0.x, d0.w, d1.z, d2.y};
        float dy[4] = {d0.y, d1.x, d1.w, d2.z};
        float dz[4] = {d0.z, d1.y, d2.x, d2.w};
        float ww[4] = {w.x,  w.y,  w.z,  w.w};
        int   ss[4] = {s.x,  s.y,  s.z,  s.w};
        int   tt[4] = {t.x,  t.y,  t.z,  t.w};

#pragma unroll
        for (int k = 0; k < 4; ++k) {
            float c  = -2.0f * ww[k];
            float xx = c * dx[k] * dx[k];
            float xy = c * dx[k] * dy[k];
            float xz = c * dx[k] * dz[k];
            float yy = c * dy[k] * dy[k];
            float yz = c * dy[k] * dz[k];
            float zz = c * dz[k] * dz[k];
            int g0 = batch[ss[k]];
            int g1 = batch[tt[k]];
            float* a0 = &acc[g0 * ACC_STRIDE];
            lds_add(a0 + 0, xx); lds_add(a0 + 1, xy); lds_add(a0 + 2, xz);
            lds_add(a0 + 3, yy); lds_add(a0 + 4, yz); lds_add(a0 + 5, zz);
            float* a1 = &acc[g1 * ACC_STRIDE];
            lds_add(a1 + 0, xx); lds_add(a1 + 1, xy); lds_add(a1 + 2, xz);
            lds_add(a1 + 3, yy); lds_add(a1 + 4, yz); lds_add(a1 + 5, zz);
        }
    }

    // Tail edges (E % 4)
    const int tail_start = nquads << 2;
    if (tid < (E - tail_start)) {
        int e = tail_start + tid;
        float ddx = disp[e * 3 + 0], ddy = disp[e * 3 + 1], ddz = disp[e * 3 + 2];
        float c = -2.0f * edge_w[e];
        int g0 = batch[edge_index[e]];
        int g1 = batch[edge_index[E + e]];
        float xx = c * ddx * ddx, xy = c * ddx * ddy, xz = c * ddx * ddz;
        float yy = c * ddy * ddy, yz = c * ddy * ddz, zz = c * ddz * ddz;
        float* a0 = &acc[g0 * ACC_STRIDE];
        lds_add(a0 + 0, xx); lds_add(a0 + 1, xy); lds_add(a0 + 2, xz);
        lds_add(a0 + 3, yy); lds_add(a0 + 4, yz); lds_add(a0 + 5, zz);
        float* a1 = &acc[g1 * ACC_STRIDE];
        lds_add(a1 + 0, xx); lds_add(a1 + 1, xy); lds_add(a1 + 2, xz);
        lds_add(a1 + 3, yy); lds_add(a1 + 4, yz); lds_add(a1 + 5, zz);
    }

    __syncthreads();

    if (partials) {
        // Plain coalesced stores of this block's 384-float partial.
        for (int i = threadIdx.x; i < NPART; i += blockDim.x) {
            int g = i / NCOMP, c = i % NCOMP;
            partials[(size_t)blockIdx.x * NPART + i] = acc[g * ACC_STRIDE + c];
        }
    } else {
        // Fallback only (tiny ws): NATIVE agent-scope fp32 atomics, not CAS.
        for (int i = threadIdx.x; i < NG * 9; i += blockDim.x) {
            int g = i / 9, ij = i % 9, r = ij / 3, cc = ij % 3;
            int lo = r < cc ? r : cc;
            int hi = r < cc ? cc : r;
            int comp = (lo == 0) ? hi : ((lo == 1) ? 2 + hi : 5);
            __hip_atomic_fetch_add(&out[i], acc[g * ACC_STRIDE + comp],
                                   __ATOMIC_RELAXED, __HIP_MEMORY_SCOPE_AGENT);
        }
    }
}

// Stage 1: 64 blocks x NPART threads; block j sums partials b = j, j+64, ...
__global__ __launch_bounds__(NPART) void reduce1_kernel(
    const float* __restrict__ partials, float* __restrict__ partials2, int nblk)
{
    int i = threadIdx.x;          // component index 0..383
    int j = blockIdx.x;           // 0..63
    float s = 0.0f;
    for (int b = j; b < nblk; b += RED1_BLOCKS)
        s += partials[(size_t)b * NPART + i];
    partials2[(size_t)j * NPART + i] = s;
}

// Stage 2: 1 block x NPART threads; expand symmetric 6 -> full 3x3 and store.
__global__ __launch_bounds__(NPART) void reduce2_kernel(
    const float* __restrict__ partials2, float* __restrict__ out)
{
    int i = threadIdx.x;          // 0..383
    float s = 0.0f;
#pragma unroll
    for (int j = 0; j < RED1_BLOCKS; ++j)
        s += partials2[(size_t)j * NPART + i];
    int g = i / NCOMP, c = i % NCOMP;
    // comp c -> (row,col): 0:(0,0) 1:(0,1) 2:(0,2) 3:(1,1) 4:(1,2) 5:(2,2)
    int r   = (c < 3) ? 0 : ((c < 5) ? 1 : 2);
    int col = (c < 3) ? c : ((c < 5) ? c - 2 : 2);
    out[g * 9 + r * 3 + col] = s;
    if (r != col) out[g * 9 + col * 3 + r] = s;
}

extern "C" void kernel_launch(void* const* d_in, const int* in_sizes, int n_in,
                              void* d_out, int out_size, void* d_ws, size_t ws_size,
                              hipStream_t stream) {
    const float* disp       = (const float*)d_in[0];
    const float* edge_w     = (const float*)d_in[1];
    const int*   edge_index = (const int*)d_in[2];
    const int*   batch      = (const int*)d_in[3];
    float*       out        = (float*)d_out;

    const int E = in_sizes[1];

    // Pick main-grid size that fits ws: (nblk + 64) partials of 384 floats.
    int nblk = 2048;
    while (nblk >= RED1_BLOCKS &&
           ws_size < (size_t)(nblk + RED1_BLOCKS) * NPART * sizeof(float))
        nblk >>= 1;

    if (nblk >= RED1_BLOCKS) {
        float* partials  = (float*)d_ws;
        float* partials2 = partials + (size_t)nblk * NPART;
        virial_partials<<<nblk, 256, 0, stream>>>(
            disp, edge_w, edge_index, batch, partials, nullptr, E);
        reduce1_kernel<<<RED1_BLOCKS, NPART, 0, stream>>>(partials, partials2, nblk);
        reduce2_kernel<<<1, NPART, 0, stream>>>(partials2, out);
    } else {
        // ws too small: zero out, then native-atomic epilogue.
        zero_out_kernel<<<(NG * 9 + 255) / 256, 256, 0, stream>>>(out, NG * 9);
        virial_partials<<<2048, 256, 0, stream>>>(
            disp, edge_w, edge_index, batch, nullptr, out, E);
    }
}